// Round 19
// baseline (253.498 us; speedup 1.0000x reference)
//
#include <hip/hip_runtime.h>
#include <math.h>

// Problem constants (match reference setup_inputs)
constexpr int B = 128, T = 128, F = 2048, KW = 5;
#define ALPHA 0.9f
#define BETA  0.1f
#define DECAY 0.9f
#define GAMMA 0.5f

// native clang vector types
typedef float v4f __attribute__((ext_vector_type(4)));

// Full-range atan, max err ~2e-6 rad (validated R6/R7: absmax unchanged).
__device__ __forceinline__ float atan_fast(float z) {
    float az  = __builtin_fabsf(z);
    float inv = __builtin_amdgcn_rcpf(az);
    bool  big = az > 1.0f;
    float u   = big ? inv : az;
    float u2  = u * u;
    float p   = fmaf(u2, -0.01172120f, 0.05265332f);
    p = fmaf(u2, p, -0.11643287f);
    p = fmaf(u2, p,  0.19354346f);
    p = fmaf(u2, p, -0.33262347f);
    p = fmaf(u2, p,  0.99997726f);
    float r = u * p;
    r = big ? (1.57079632679f - r) : r;
    return copysignf(r, z);
}

// R17 theory: REQUEST SIZE. The harness's fillBufferAligned hits 6.7 TB/s
// (84% peak) at 9.5% occupancy with dwordx4 stores; the float4 copy ubench
// hits 6.3. Every plateaued variant of ours (8 kernels, 2.6-3.0 TB/s) moves
// <=8 B/lane (512 B/wave-request). If per-CU BW = VMEM request rate x
// bytes/request, 8B/lane caps at half the 16B rate: 2.9 = 6.3/2 fits.
// This kernel: one thread owns 4 consecutive f's -> ALL traffic (pass-1
// loads, pass-2 loads, spike stores) is dwordx4, 1 KB/wave-instruction.
// 256 blocks x 256 thr = 4 waves/CU (fill proves wide requests don't need
// occupancy). 4 independent LIF chains/thread = VALU ILP; split & XCD remap
// dropped (measured neutral). Fast-atan + NT stores kept (validated).
__global__ __launch_bounds__(256, 1) void lif_fused_kernel(
    const float* __restrict__ x,        // [B,T,F]
    const float* __restrict__ thr0p,    // scalar
    const float* __restrict__ convw,    // [1,1,KW]
    const float* __restrict__ convb,    // [1]
    const float* __restrict__ sattn,    // [1]
    float* __restrict__ out)            // [B*T*F] spikes ++ [B*F] mem
{
    const int tid   = blockIdx.x * blockDim.x + threadIdx.x;
    const int fquad = tid & (F / 4 - 1);    // 0..511
    const int b     = tid >> 9;             // tid / (F/4)
    const int f     = fquad * 4;

    const float w0 = convw[0], w1 = convw[1], w2 = convw[2],
                w3 = convw[3], w4 = convw[4];
    const float cb   = convb[0];
    const float thr0 = thr0p[0];
    const float sa   = sattn[0];

    const float* xp = x + (size_t)b * T * F + f;

    // ---- pass 1: sum of x over t (8 partial sums, 8 dwordx4 in flight) ----
    v4f s0 = 0.f, s1 = 0.f, s2 = 0.f, s3 = 0.f,
        s4 = 0.f, s5 = 0.f, s6 = 0.f, s7 = 0.f;
#pragma unroll 2
    for (int t = 0; t < T; t += 8) {
        v4f v0 = *(const v4f*)(xp + (size_t)(t + 0) * F);
        v4f v1 = *(const v4f*)(xp + (size_t)(t + 1) * F);
        v4f v2 = *(const v4f*)(xp + (size_t)(t + 2) * F);
        v4f v3 = *(const v4f*)(xp + (size_t)(t + 3) * F);
        v4f v4 = *(const v4f*)(xp + (size_t)(t + 4) * F);
        v4f v5 = *(const v4f*)(xp + (size_t)(t + 5) * F);
        v4f v6 = *(const v4f*)(xp + (size_t)(t + 6) * F);
        v4f v7 = *(const v4f*)(xp + (size_t)(t + 7) * F);
        s0 += v0; s1 += v1; s2 += v2; s3 += v3;
        s4 += v4; s5 += v5; s6 += v6; s7 += v7;
    }
    v4f sx = ((s0 + s1) + (s2 + s3)) + ((s4 + s5) + (s6 + s7));

    // edge values (L2/L3-warm re-reads)
    v4f e0  = *(const v4f*)(xp);                      // x[0]
    v4f e1  = *(const v4f*)(xp + (size_t)F);          // x[1]
    v4f em2 = *(const v4f*)(xp + (size_t)(T - 2) * F);// x[T-2]
    v4f em1 = *(const v4f*)(xp + (size_t)(T - 1) * F);// x[T-1]

    // sum_t conv[t] = W*sum_t x - (w3+w4)x[0] - w4 x[1] - w0 x[T-2] - (w0+w1)x[T-1] + T*cb
    const float W = ((w0 + w1) + (w2 + w3)) + w4;
    v4f csum = W * sx + (float)T * cb
             - (w3 + w4) * e0 - w4 * e1 - w0 * em2 - (w0 + w1) * em1;

    // ---- spatial attention gate (per component) ----
    v4f scale;
#pragma unroll
    for (int j = 0; j < 4; ++j) {
        float z = sa * (csum[j] * (1.0f / (float)T));
        scale[j] = 1.0f + GAMMA * (1.0f / (1.0f + expf(-z)));
    }

    // ---- pass 2: rolling conv + LIF recurrence, all dwordx4 ----
    const float PIH    = 1.57079632679f;        // pi/2
    const float INV2PI = 0.15915494309f;        // 1/(2*pi)
    const float thc    = (1.0f - ALPHA) * thr0;

    v4f mem = 0.f;
    v4f thr = thr0;
    v4f h1 = 0.f, h2 = 0.f;
    // window regs: a=x[t-2], bb=x[t-1], c=x[t], d=x[t+1]
    v4f a = 0.f, bb = 0.f, c = e0, d = e1;

    float* sp = out + (size_t)b * T * F + f;                  // spikes [B,T,F]
    float* mp = out + (size_t)B * T * F + (size_t)b * F + f;  // mem [B,F]

    auto lif_step = [&](int t, v4f e) {
        v4f ct = w0 * a + w1 * bb + w2 * c + w3 * d + w4 * e + cb;
        mem = DECAY * mem + ct * scale;
        v4f spike;
#pragma unroll
        for (int j = 0; j < 4; ++j)
            spike[j] = fmaf(atan_fast(PIH * (mem[j] - thr[j])), INV2PI, 0.25f);
        v4f avg = (h1 + h2 + spike) * (1.0f / 3.0f);
        h1 = h2; h2 = spike;
        thr = ALPHA * thr + (BETA * avg + thc);
        mem = mem - spike * thr;
        __builtin_nontemporal_store(spike, (v4f*)(sp + (size_t)t * F));
        a = bb; bb = c; c = d; d = e;
    };

#pragma unroll 8
    for (int t = 0; t < T - 2; ++t) {
        v4f e = *(const v4f*)(xp + (size_t)(t + 2) * F);
        lif_step(t, e);
    }
    lif_step(T - 2, (v4f)0.f);   // e = 0 (zero pad)
    lif_step(T - 1, (v4f)0.f);   // d = e = 0

    __builtin_nontemporal_store(mem, (v4f*)mp);
}

extern "C" void kernel_launch(void* const* d_in, const int* in_sizes, int n_in,
                              void* d_out, int out_size, void* d_ws, size_t ws_size,
                              hipStream_t stream) {
    const float* x     = (const float*)d_in[0];
    const float* thr0  = (const float*)d_in[1];
    const float* convw = (const float*)d_in[2];
    const float* convb = (const float*)d_in[3];
    const float* sattn = (const float*)d_in[4];
    float* out = (float*)d_out;

    const int total = B * F / 4;        // one thread per 4 (b,f) series
    const int block = 256;
    const int grid  = total / block;    // 256 blocks

    lif_fused_kernel<<<grid, block, 0, stream>>>(x, thr0, convw, convb, sattn, out);
}